// Round 1
// baseline (2512.387 us; speedup 1.0000x reference)
//
#include <hip/hip_runtime.h>
#include <math.h>

#define ACT_LRELU  0
#define ACT_SIGMAP 1
#define ACT_SQUARE 2

static __device__ __forceinline__ float lrelu(float x) { return x >= 0.f ? x : 0.2f * x; }

// -------------------------------------------------------------------------
// Small conv: k=3, pad=1, T=64. Two independent paths fused via blockIdx.z.
// Block: 256 thr = 16 co-quads (ty) x 16 t-quads (tx); tile = 64 co x 64 t.
// -------------------------------------------------------------------------
__global__ void __launch_bounds__(256) conv_small(
    const float* __restrict__ inm, const float* __restrict__ ing,
    const float* __restrict__ Wm, const float* __restrict__ Bm,
    const float* __restrict__ Wg, const float* __restrict__ Bg,
    float* __restrict__ outm, float* __restrict__ outg,
    int Cin, int Cout, int actm, int actg)
{
  const int p = blockIdx.z;
  const float* in = p ? ing : inm;
  const float* W  = p ? Wg  : Wm;
  const float* Bs = p ? Bg  : Bm;
  float* out      = p ? outg : outm;
  const int act   = p ? actg : actm;

  const int coBase = blockIdx.x * 64;
  const int b   = blockIdx.y;
  const int tid = threadIdx.x;
  const int tx  = tid & 15;   // t quad
  const int ty  = tid >> 4;   // co quad

  __shared__ __align__(16) float inS[64][68];   // [ci][u], u = t_in + 1, u in [0,66)
  __shared__ __align__(16) float wS[64][192];   // [ci][co_l*3 + k]

  float acc[4][4] = {};

  for (int ci0 = 0; ci0 < Cin; ci0 += 64) {
    for (int e = tid; e < 64 * 66; e += 256) {
      int ci = e / 66, u = e - ci * 66;
      int tin = u - 1;
      float v = 0.f;
      if (tin >= 0 && tin < 64) v = in[(size_t)(b * Cin + ci0 + ci) * 64 + tin];
      inS[ci][u] = v;
    }
    for (int e = tid; e < 64 * 64; e += 256) {
      int col = e >> 6, ci = e & 63;
      const float* wp = W + ((size_t)(coBase + col) * Cin + (ci0 + ci)) * 3;
      wS[ci][col * 3 + 0] = wp[0];
      wS[ci][col * 3 + 1] = wp[1];
      wS[ci][col * 3 + 2] = wp[2];
    }
    __syncthreads();
    for (int ci = 0; ci < 64; ++ci) {
      const float4* ip = reinterpret_cast<const float4*>(&inS[ci][tx * 4]);
      float4 i03 = ip[0];
      float2 i45 = *reinterpret_cast<const float2*>(&inS[ci][tx * 4 + 4]);
      float iv[6] = {i03.x, i03.y, i03.z, i03.w, i45.x, i45.y};
      const float4* wp4 = reinterpret_cast<const float4*>(&wS[ci][ty * 12]);
      float4 wa = wp4[0], wb = wp4[1], wc = wp4[2];
      float w[12] = {wa.x, wa.y, wa.z, wa.w, wb.x, wb.y, wb.z, wb.w, wc.x, wc.y, wc.z, wc.w};
#pragma unroll
      for (int cc = 0; cc < 4; ++cc)
#pragma unroll
        for (int tt = 0; tt < 4; ++tt)
          acc[cc][tt] += w[cc * 3 + 0] * iv[tt] + w[cc * 3 + 1] * iv[tt + 1] + w[cc * 3 + 2] * iv[tt + 2];
    }
    __syncthreads();
  }

#pragma unroll
  for (int cc = 0; cc < 4; ++cc) {
    int co = coBase + ty * 4 + cc;
    float bi = Bs[co];
    float sf = 0.f, df = 0.f;
    if (act == ACT_SIGMAP) {
      // geomspace(20, 11025, 128) oscillator bands
      double lg = log(551.25);                       // 11025/20
      double stop  = 20.0 * exp(lg * (double)co / 127.0);
      double start = (co == 0) ? 0.0 : 20.0 * exp(lg * (double)(co - 1) / 127.0);
      sf = (float)start;
      df = (float)(stop - start);
    }
    float4 v;
    float* vp = &v.x;
#pragma unroll
    for (int tt = 0; tt < 4; ++tt) {
      float z = acc[cc][tt] + bi;
      if (act == ACT_LRELU)       z = lrelu(z);
      else if (act == ACT_SIGMAP) z = sf + df / (1.f + expf(-z));
      else                        z = z * z;
      vp[tt] = z;
    }
    *reinterpret_cast<float4*>(&out[(size_t)(b * Cout + co) * 64 + tx * 4]) = v;
  }
}

// -------------------------------------------------------------------------
// Noise-path conv: nearest-x2 upsample + k=7 pad=3 conv, folded into a
// 4-tap conv on the UN-repeated input with parity-combined weights.
//   even out t=2s: taps m=s-2..s+1, weights {w0, w1+w2, w3+w4, w5+w6}
//   odd  out t=2s+1: taps m=s-1..s+2, weights {w0+w1, w2+w3, w4+w5, w6}
// Block: 256 thr = 16 co-quads x 16 s-quads; tile = 64 co x 64 s (=128 t out).
// -------------------------------------------------------------------------
__global__ void __launch_bounds__(256) conv_noise(
    const float* __restrict__ in, const float* __restrict__ W,
    const float* __restrict__ Bs, float* __restrict__ out,
    int Cin, int Tin)
{
  const int co0 = blockIdx.x * 64;
  const int s0  = blockIdx.y * 64;
  const int b   = blockIdx.z;
  const int tid = threadIdx.x;
  const int tx  = tid & 15;
  const int ty  = tid >> 4;

  __shared__ __align__(16) float inS[16][72];    // [ci][u], m = s0-2+u
  __shared__ __align__(16) float wS[16][512];    // [ci][col*8 + q], q: 4 even + 4 odd

  float accE[4][4] = {};
  float accO[4][4] = {};

  for (int ci0 = 0; ci0 < Cin; ci0 += 16) {
    for (int e = tid; e < 16 * 72; e += 256) {
      int ci = e / 72, u = e - ci * 72;
      int m = s0 - 2 + u;
      float v = 0.f;
      if (m >= 0 && m < Tin) v = in[(size_t)(b * Cin + ci0 + ci) * Tin + m];
      inS[ci][u] = v;
    }
    for (int e = tid; e < 16 * 64; e += 256) {
      int ci = e & 15, col = e >> 4;
      const float* wp = W + ((size_t)(co0 + col) * Cin + (ci0 + ci)) * 7;
      float w0 = wp[0], w1 = wp[1], w2 = wp[2], w3 = wp[3], w4 = wp[4], w5 = wp[5], w6 = wp[6];
      float* d = &wS[ci][col * 8];
      d[0] = w0;      d[1] = w1 + w2; d[2] = w3 + w4; d[3] = w5 + w6;
      d[4] = w0 + w1; d[5] = w2 + w3; d[6] = w4 + w5; d[7] = w6;
    }
    __syncthreads();
#pragma unroll 4
    for (int ci = 0; ci < 16; ++ci) {
      const float4* ip = reinterpret_cast<const float4*>(&inS[ci][tx * 4]);
      float4 a0 = ip[0], a1 = ip[1];
      float iv[8] = {a0.x, a0.y, a0.z, a0.w, a1.x, a1.y, a1.z, a1.w};
      const float4* wp4 = reinterpret_cast<const float4*>(&wS[ci][ty * 32]);
#pragma unroll
      for (int cc = 0; cc < 4; ++cc) {
        float4 we = wp4[cc * 2], wo = wp4[cc * 2 + 1];
#pragma unroll
        for (int ss = 0; ss < 4; ++ss) {
          accE[cc][ss] += we.x * iv[ss] + we.y * iv[ss + 1] + we.z * iv[ss + 2] + we.w * iv[ss + 3];
          accO[cc][ss] += wo.x * iv[ss + 1] + wo.y * iv[ss + 2] + wo.z * iv[ss + 3] + wo.w * iv[ss + 4];
        }
      }
    }
    __syncthreads();
  }

  const int T2 = Tin * 2;
#pragma unroll
  for (int cc = 0; cc < 4; ++cc) {
    int co = co0 + ty * 4 + cc;
    float bi = Bs[co];
    float4 v0, v1;
    v0.x = lrelu(accE[cc][0] + bi); v0.y = lrelu(accO[cc][0] + bi);
    v0.z = lrelu(accE[cc][1] + bi); v0.w = lrelu(accO[cc][1] + bi);
    v1.x = lrelu(accE[cc][2] + bi); v1.y = lrelu(accO[cc][2] + bi);
    v1.z = lrelu(accE[cc][3] + bi); v1.w = lrelu(accO[cc][3] + bi);
    float* op = out + (size_t)(b * 512 + co) * T2 + 2 * (s0 + tx * 4);
    reinterpret_cast<float4*>(op)[0] = v0;
    reinterpret_cast<float4*>(op)[1] = v1;
  }
}

// -------------------------------------------------------------------------
// Final noise conv: 512 -> 17 channels, k=3 pad=1, T=1024, output squared.
// Block: 256 thr = 16 co-groups x 16 t-quads; tile = 17 co x 64 t.
// cog 0 handles co {0,16}; cog 1..15 handle co {cog}.
// -------------------------------------------------------------------------
__global__ void __launch_bounds__(256) conv_nl(
    const float* __restrict__ in, const float* __restrict__ W,
    const float* __restrict__ Bs, float* __restrict__ out)
{
  const int t0  = blockIdx.x * 64;
  const int b   = blockIdx.y;
  const int tid = threadIdx.x;
  const int tx  = tid & 15;
  const int cog = tid >> 4;

  __shared__ __align__(16) float inS[64][68];
  __shared__ float wS[64][52];

  float acc0[4] = {}, acc1[4] = {};
  const bool has2 = (cog == 0);

  for (int ci0 = 0; ci0 < 512; ci0 += 64) {
    for (int e = tid; e < 64 * 66; e += 256) {
      int ci = e / 66, u = e - ci * 66;
      int tin = t0 - 1 + u;
      float v = 0.f;
      if (tin >= 0 && tin < 1024) v = in[(size_t)(b * 512 + ci0 + ci) * 1024 + tin];
      inS[ci][u] = v;
    }
    for (int e = tid; e < 64 * 17; e += 256) {
      int col = e / 64, ci = e & 63;
      const float* wp = W + ((size_t)col * 512 + (ci0 + ci)) * 3;
      wS[ci][col * 3 + 0] = wp[0];
      wS[ci][col * 3 + 1] = wp[1];
      wS[ci][col * 3 + 2] = wp[2];
    }
    __syncthreads();
    for (int ci = 0; ci < 64; ++ci) {
      const float4* ip = reinterpret_cast<const float4*>(&inS[ci][tx * 4]);
      float4 i03 = ip[0];
      float2 i45 = *reinterpret_cast<const float2*>(&inS[ci][tx * 4 + 4]);
      float iv[6] = {i03.x, i03.y, i03.z, i03.w, i45.x, i45.y};
      float wA0 = wS[ci][cog * 3], wA1 = wS[ci][cog * 3 + 1], wA2 = wS[ci][cog * 3 + 2];
#pragma unroll
      for (int tt = 0; tt < 4; ++tt)
        acc0[tt] += wA0 * iv[tt] + wA1 * iv[tt + 1] + wA2 * iv[tt + 2];
      if (has2) {
        float wB0 = wS[ci][48], wB1 = wS[ci][49], wB2 = wS[ci][50];
#pragma unroll
        for (int tt = 0; tt < 4; ++tt)
          acc1[tt] += wB0 * iv[tt] + wB1 * iv[tt + 1] + wB2 * iv[tt + 2];
      }
    }
    __syncthreads();
  }

  {
    float bi = Bs[cog];
#pragma unroll
    for (int tt = 0; tt < 4; ++tt) {
      float z = acc0[tt] + bi;
      out[(size_t)(b * 17 + cog) * 1024 + t0 + tx * 4 + tt] = z * z;
    }
    if (has2) {
      float bi2 = Bs[16];
#pragma unroll
      for (int tt = 0; tt < 4; ++tt) {
        float z = acc1[tt] + bi2;
        out[(size_t)(b * 17 + 16) * 1024 + t0 + tx * 4 + tt] = z * z;
      }
    }
  }
}

// -------------------------------------------------------------------------
// Noise bank: per 32-sample frame, 17-bin real DFT * mags, inverse, store.
// One thread per frame (16*1024 frames).
// -------------------------------------------------------------------------
__global__ void __launch_bounds__(256) noise_filter(
    const float* __restrict__ noise, const float* __restrict__ mags,
    float* __restrict__ filt)
{
  __shared__ float ct[32], st[32];
  int tid = threadIdx.x;
  if (tid < 32) {
    double a = (double)tid * (3.14159265358979323846 / 16.0);
    ct[tid] = (float)cos(a);
    st[tid] = (float)sin(a);
  }
  __syncthreads();

  int fidx = blockIdx.x * 256 + tid;
  int b = fidx >> 10, i = fidx & 1023;

  float xv[32];
#pragma unroll
  for (int n = 0; n < 32; ++n) {
    int idx = i * 16 + n;
    xv[n] = (idx < 16384) ? noise[(size_t)b * 16384 + idx] : 0.f;  // zero pad tail
  }

  float Yr[17], Yi[17];
#pragma unroll
  for (int k = 0; k <= 16; ++k) {
    float xr = 0.f, xi = 0.f;
    int kk = 0;
#pragma unroll
    for (int n = 0; n < 32; ++n) {
      xr += xv[n] * ct[kk];
      xi -= xv[n] * st[kk];
      kk = (kk + k) & 31;
    }
    float m = mags[((size_t)b * 17 + k) * 1024 + i];
    Yr[k] = xr * m;
    Yi[k] = xi * m;
  }

  float* fo = filt + ((size_t)b * 1024 + i) * 32;
#pragma unroll
  for (int n = 0; n < 32; ++n) {
    float v = Yr[0] + ((n & 1) ? -Yr[16] : Yr[16]);
    int kk = n;
#pragma unroll
    for (int k = 1; k <= 15; ++k) {
      v += 2.f * (Yr[k] * ct[kk] - Yi[k] * st[kk]);
      kk = (kk + n) & 31;
    }
    fo[n] = v * (1.f / 32.f);
  }
}

// -------------------------------------------------------------------------
// Oscillator bank. Linear x256 upsample (half-pixel, edge-clamped) done
// inline; phase accumulated in f64 (errors amplify over 16384 samples).
// -------------------------------------------------------------------------
static __device__ __forceinline__ float lerp64s(const float* __restrict__ row, int t)
{
  float ic = ((float)t - 127.5f) * (1.0f / 256.0f);
  float fl = floorf(ic);
  float w  = ic - fl;
  int i0 = (int)fl;
  int ia = i0 < 0 ? 0 : (i0 > 63 ? 63 : i0);
  int i1 = i0 + 1;
  int ib = i1 < 0 ? 0 : (i1 > 63 ? 63 : i1);
  return row[ia] * (1.f - w) + row[ib] * w;
}

#define PHK (6.283185307179586476925287 / 22050.0)

// Pass 1: per (b,osc) row, exclusive prefix of per-64-chunk phase sums.
__global__ void __launch_bounds__(256) osc_phase(
    const float* __restrict__ fsm, double* __restrict__ phaseBase)
{
  const int o = blockIdx.x, b = blockIdx.y;
  const float* frow = fsm + (size_t)(b * 128 + o) * 64;
  const int tid = threadIdx.x;
  double local = 0.0;
  const int tbase = tid * 64;
  for (int j = 0; j < 64; ++j) {
    float f = lerp64s(frow, tbase + j);
    f = fminf(fmaxf(f, 20.f), 11025.f);
    local += (double)f * PHK;
  }
  __shared__ double ps[256];
  ps[tid] = local;
  __syncthreads();
  for (int off = 1; off < 256; off <<= 1) {
    double v = (tid >= off) ? ps[tid - off] : 0.0;
    __syncthreads();
    ps[tid] += v;
    __syncthreads();
  }
  phaseBase[(size_t)(b * 128 + o) * 256 + tid] = ps[tid] - local;  // exclusive
}

// Pass 2: per (b, 64-sample chunk): replay phase, sum sin*amp over 128 osc,
// add overlap-added filtered noise, write final output.
__global__ void __launch_bounds__(128) osc_sum(
    const float* __restrict__ fsm, const float* __restrict__ lsm,
    const double* __restrict__ phaseBase, const float* __restrict__ filt,
    float* __restrict__ out)
{
  const int c = blockIdx.x, b = blockIdx.y;
  const int tid = threadIdx.x;
  __shared__ float contrib[128][65];
  __shared__ float part[2][64];
  const int o = tid;
  const float* frow = fsm + (size_t)(b * 128 + o) * 64;
  const float* arow = lsm + (size_t)(b * 128 + o) * 64;
  double ph = phaseBase[(size_t)(b * 128 + o) * 256 + c];
  const int tbase = c * 64;
  for (int j = 0; j < 64; ++j) {
    int t = tbase + j;
    float f = lerp64s(frow, t);
    f = fminf(fmaxf(f, 20.f), 11025.f);
    ph += (double)f * PHK;
    double rev = ph * 0.15915494309189533576888;  // 1/(2pi)
    rev -= floor(rev);
    float s = sinpif(2.f * (float)rev);
    float a = lerp64s(arow, t);
    contrib[o][j] = s * a;
  }
  __syncthreads();
  int half = tid >> 6, tl = tid & 63;
  float sum = 0.f;
  for (int oo = 0; oo < 64; ++oo) sum += contrib[half * 64 + oo][tl];
  part[half][tl] = sum;
  __syncthreads();
  if (tid < 64) {
    int t = tbase + tid;
    float v = part[0][tid] + part[1][tid];
    int i0 = t >> 4, r = t & 15;
    v += filt[((size_t)(b << 10) + i0) * 32 + r];
    if (i0 > 0) v += filt[((size_t)(b << 10) + i0 - 1) * 32 + 16 + r];
    out[(size_t)b * 16384 + t] = v;
  }
}

// -------------------------------------------------------------------------
extern "C" void kernel_launch(void* const* d_in, const int* in_sizes, int n_in,
                              void* d_out, int out_size, void* d_ws, size_t ws_size,
                              hipStream_t stream)
{
  (void)in_sizes; (void)n_in; (void)out_size; (void)ws_size;

  const float* x     = (const float*)d_in[0];
  const float* noise = (const float*)d_in[1];
  const float* mw0 = (const float*)d_in[2];  const float* mb0 = (const float*)d_in[3];
  const float* mw1 = (const float*)d_in[4];  const float* mb1 = (const float*)d_in[5];
  const float* mw2 = (const float*)d_in[6];  const float* mb2 = (const float*)d_in[7];
  const float* mw3 = (const float*)d_in[8];  const float* mb3 = (const float*)d_in[9];
  const float* fw  = (const float*)d_in[10]; const float* fb  = (const float*)d_in[11];
  const float* gw0 = (const float*)d_in[12]; const float* gb0 = (const float*)d_in[13];
  const float* gw1 = (const float*)d_in[14]; const float* gb1 = (const float*)d_in[15];
  const float* gw2 = (const float*)d_in[16]; const float* gb2 = (const float*)d_in[17];
  const float* gw3 = (const float*)d_in[18]; const float* gb3 = (const float*)d_in[19];
  const float* lw  = (const float*)d_in[20]; const float* lb  = (const float*)d_in[21];
  const float* nw0 = (const float*)d_in[22]; const float* nb0 = (const float*)d_in[23];
  const float* nw1 = (const float*)d_in[24]; const float* nb1 = (const float*)d_in[25];
  const float* nw2 = (const float*)d_in[26]; const float* nb2 = (const float*)d_in[27];
  const float* nw3 = (const float*)d_in[28]; const float* nb3 = (const float*)d_in[29];
  const float* nlw = (const float*)d_in[30]; const float* nlb = (const float*)d_in[31];

  float* ws = (float*)d_ws;
  // workspace layout (floats); total = 14,696,448 floats = 58.8 MB
  float*  nbufA = ws;                       // 4,194,304  (noise l1/l3 out; also aliases hm/hg)
  float*  nbufB = ws + 4194304;             // 8,388,608  (noise l2/l4 out)
  float*  fsm   = ws + 12582912;            // 131,072  [16][128][64]
  float*  lsm   = ws + 12713984;            // 131,072
  float*  nl    = ws + 12845056;            // 278,528  [16][17][1024]
  float*  filt  = ws + 13123584;            // 524,288  [16][1024][32]
  double* phaseBase = (double*)(ws + 13647872);  // 524,288 doubles [16][128][256]
  // m/g path ping-pong buffers alias nbufA (freed before noise path runs)
  float* hm0 = nbufA;
  float* hm1 = nbufA + 524288;
  float* hg0 = nbufA + 1048576;
  float* hg1 = nbufA + 1572864;

  float* out = (float*)d_out;

  // frequency (m) + loudness (g) paths, fused
  conv_small<<<dim3(8, 16, 2), 256, 0, stream>>>(x, x, mw0, mb0, gw0, gb0, hm0, hg0, 128, 512, ACT_LRELU, ACT_LRELU);
  conv_small<<<dim3(8, 16, 2), 256, 0, stream>>>(hm0, hg0, mw1, mb1, gw1, gb1, hm1, hg1, 512, 512, ACT_LRELU, ACT_LRELU);
  conv_small<<<dim3(8, 16, 2), 256, 0, stream>>>(hm1, hg1, mw2, mb2, gw2, gb2, hm0, hg0, 512, 512, ACT_LRELU, ACT_LRELU);
  conv_small<<<dim3(8, 16, 2), 256, 0, stream>>>(hm0, hg0, mw3, mb3, gw3, gb3, hm1, hg1, 512, 512, ACT_LRELU, ACT_LRELU);
  conv_small<<<dim3(2, 16, 2), 256, 0, stream>>>(hm1, hg1, fw, fb, lw, lb, fsm, lsm, 512, 128, ACT_SIGMAP, ACT_SQUARE);

  // noise-envelope path (repeat-x2 folded into parity weights)
  conv_noise<<<dim3(8, 1, 16), 256, 0, stream>>>(x,     nw0, nb0, nbufA, 128, 64);
  conv_noise<<<dim3(8, 2, 16), 256, 0, stream>>>(nbufA, nw1, nb1, nbufB, 512, 128);
  conv_noise<<<dim3(8, 4, 16), 256, 0, stream>>>(nbufB, nw2, nb2, nbufA, 512, 256);
  conv_noise<<<dim3(8, 8, 16), 256, 0, stream>>>(nbufA, nw3, nb3, nbufB, 512, 512);
  conv_nl<<<dim3(16, 16), 256, 0, stream>>>(nbufB, nlw, nlb, nl);

  // filtered noise frames
  noise_filter<<<dim3(64), 256, 0, stream>>>(noise, nl, filt);

  // oscillator bank + final sum (includes overlap-add of noise frames)
  osc_phase<<<dim3(128, 16), 256, 0, stream>>>(fsm, phaseBase);
  osc_sum<<<dim3(256, 16), 128, 0, stream>>>(fsm, lsm, phaseBase, filt, out);
}